// Round 3
// baseline (491.099 us; speedup 1.0000x reference)
//
#include <hip/hip_runtime.h>
#include <stdint.h>
#include <stddef.h>

// Problem constants (MultiHeadAttention_52759378264454)
constexpr int T_SEQ = 1024;
constexpr int BATCH = 8;
constexpr int DIN   = 256;
constexpr int NH    = 8;
constexpr int EH    = 512;
constexpr int HE    = NH * EH;   // 4096
constexpr float SCALE = 0.044194173824159216f; // 1/sqrt(512)

typedef __attribute__((ext_vector_type(8))) short s16x8;
typedef __attribute__((ext_vector_type(4))) short s16x4;
typedef __attribute__((ext_vector_type(4))) float f32x4_t;

__device__ __forceinline__ short f2bf(float f) {
  union { float f; uint32_t u; } c; c.f = f;
  uint32_t u = c.u;
  u += 0x7fffu + ((u >> 16) & 1u);   // RNE (finite values only here)
  return (short)(u >> 16);
}
__device__ __forceinline__ float bf2f(short s) {
  union { uint32_t u; float f; } c; c.u = ((uint32_t)(uint16_t)s) << 16;
  return c.f;
}

// async global->LDS, 16B per lane. LDS dest = wave-uniform base + lane*16 (HW).
__device__ __forceinline__ void gload16(const short* g, short* l) {
  __builtin_amdgcn_global_load_lds(
      (__attribute__((address_space(1))) void*)(void*)const_cast<short*>(g),
      (__attribute__((address_space(3))) void*)(void*)l, 16, 0, 0);
}

#define BAR_FENCE do { __builtin_amdgcn_s_barrier(); asm volatile("" ::: "memory"); } while (0)
#define WAITVM(N) asm volatile("s_waitcnt vmcnt(" #N ")" ::: "memory")

// ---------------------------------------------------------------------------
// 8-wave 256x256 GEMM, BK=64, double-buffered LDS (128 KiB), m201-style
// 4-phase-per-K-tile schedule with counted vmcnt (T2+T3+T4+T5).
//
// C[256,256] += A[256,K] * B[256,K]^T, A/B K-major bf16.
// Waves: wm = wv>>2 (2), wn = wv&3 (4); per-wave C = 128x64 = 8mi x 4ni frags.
// LDS buf (per K-tile, 64KB): A halves (by K: cols 0-31 / 32-63) at 0 and
// 8192 shorts; B halves at 16384/24576. 2 bufs (tile t -> buf t&1).
// Swizzle: within a half, row = 4 chunks of 16B; slot cp holds source chunk
// cp ^ f(row), f(row) = (row&3)^((row>>2)&3) (involution; applied on the
// pre-swizzled global source AND on the ds_read -> 2-way max = free).
// Per K-tile: P1{wait8,bar, stage t+1.Ah1, read Bh0+Ah0(mi0-3), 16 MFMA}
//             P2{stage t+1.Bh1, read Ah0(mi4-7), 16 MFMA}
//             P3{wait8,bar, stage t+2.Ah0, read Bh1+Ah1(mi0-3), 16 MFMA}
//             P4{stage t+2.Bh0, read Ah1(mi4-7), 16 MFMA}
// Ledger: at P1 the 8 newer loads are {t.Ah1,t.Bh1,t+1.Ah0,t+1.Bh0};
// at P3 {t+1.Ah0,t+1.Bh0,t+1.Ah1,t+1.Bh1} -> vmcnt(8) guarantees the needed
// halves landed. Last tile peels to vmcnt(4)/vmcnt(0).
// ---------------------------------------------------------------------------
template<int NT>   // K = NT*64, NT >= 2, NT even
__device__ __forceinline__ void gemm8p(const short* __restrict__ Ag, int lda,
                                       const short* __restrict__ Bg, int ldb,
                                       short* lds, f32x4_t (&acc)[8][4])
{
  const int tid  = threadIdx.x;
  const int lane = tid & 63, wv = tid >> 6;
  const int r = lane & 15, g = lane >> 4;
  const int Rw = (wv >> 2) * 128, Cw = (wv & 3) * 64;
  // read-side swizzled chunk offset (shorts); f(row) reduces to lane-only
  const int cpS = (g ^ (r & 3) ^ ((r >> 2) & 3)) * 8;

  // stage-side: load j covers chunk d = tid + j*512 of a 1024-chunk half
  int s_row[2], s_col[2], dstc[2];
#pragma unroll
  for (int j = 0; j < 2; ++j) {
    int d = tid + j * 512;
    int row = d >> 2, cp = d & 3;
    s_row[j] = row;
    s_col[j] = (cp ^ (row & 3) ^ ((row >> 2) & 3)) * 8;   // source chunk (involution)
    dstc[j]  = (wv * 64 + j * 512) * 8;                   // wave-uniform LDS base
  }

  auto stageA = [&](int t, int h) {
    short* base = lds + (t & 1) * 32768 + h * 8192;
#pragma unroll
    for (int j = 0; j < 2; ++j)
      gload16(Ag + (size_t)s_row[j] * lda + t * 64 + h * 32 + s_col[j], base + dstc[j]);
  };
  auto stageB = [&](int t, int h) {
    short* base = lds + (t & 1) * 32768 + 16384 + h * 8192;
#pragma unroll
    for (int j = 0; j < 2; ++j)
      gload16(Bg + (size_t)s_row[j] * ldb + t * 64 + h * 32 + s_col[j], base + dstc[j]);
  };
  auto rdA = [&](const short* buf, int h, int mi) -> s16x8 {
    return *(const s16x8*)(buf + h * 8192 + (Rw + mi * 16 + r) * 32 + cpS);
  };
  auto rdB = [&](const short* buf, int h, int ni) -> s16x8 {
    return *(const s16x8*)(buf + 16384 + h * 8192 + (Cw + ni * 16 + r) * 32 + cpS);
  };

  // prologue: tile0 complete + tile1 h0 halves (12 loads in flight)
  stageA(0, 0); stageB(0, 0); stageA(0, 1); stageB(0, 1);
  stageA(1, 0); stageB(1, 0);

  s16x8 a[4], b[4];
#pragma unroll 1
  for (int t = 0; t < NT; ++t) {
    const short* buf = lds + (t & 1) * 32768;
    const bool last = (t == NT - 1);
    // ---------------- P1 ----------------
    if (last) { WAITVM(4); } else { WAITVM(8); }
    BAR_FENCE;
    if (t + 1 < NT) stageA(t + 1, 1);
#pragma unroll
    for (int ni = 0; ni < 4; ++ni) b[ni] = rdB(buf, 0, ni);
#pragma unroll
    for (int mi = 0; mi < 4; ++mi) a[mi] = rdA(buf, 0, mi);
    __builtin_amdgcn_s_setprio(1);
#pragma unroll
    for (int mi = 0; mi < 4; ++mi)
#pragma unroll
      for (int ni = 0; ni < 4; ++ni)
        acc[mi][ni] = __builtin_amdgcn_mfma_f32_16x16x32_bf16(a[mi], b[ni], acc[mi][ni], 0, 0, 0);
    __builtin_amdgcn_s_setprio(0);
    // ---------------- P2 ----------------
    if (t + 1 < NT) stageB(t + 1, 1);
#pragma unroll
    for (int mi = 0; mi < 4; ++mi) a[mi] = rdA(buf, 0, mi + 4);
    __builtin_amdgcn_s_setprio(1);
#pragma unroll
    for (int mi = 0; mi < 4; ++mi)
#pragma unroll
      for (int ni = 0; ni < 4; ++ni)
        acc[mi + 4][ni] = __builtin_amdgcn_mfma_f32_16x16x32_bf16(a[mi], b[ni], acc[mi + 4][ni], 0, 0, 0);
    __builtin_amdgcn_s_setprio(0);
    // ---------------- P3 ----------------
    if (last) { WAITVM(0); } else { WAITVM(8); }
    BAR_FENCE;
    if (t + 2 < NT) stageA(t + 2, 0);
#pragma unroll
    for (int ni = 0; ni < 4; ++ni) b[ni] = rdB(buf, 1, ni);
#pragma unroll
    for (int mi = 0; mi < 4; ++mi) a[mi] = rdA(buf, 1, mi);
    __builtin_amdgcn_s_setprio(1);
#pragma unroll
    for (int mi = 0; mi < 4; ++mi)
#pragma unroll
      for (int ni = 0; ni < 4; ++ni)
        acc[mi][ni] = __builtin_amdgcn_mfma_f32_16x16x32_bf16(a[mi], b[ni], acc[mi][ni], 0, 0, 0);
    __builtin_amdgcn_s_setprio(0);
    // ---------------- P4 ----------------
    if (t + 2 < NT) stageB(t + 2, 0);
#pragma unroll
    for (int mi = 0; mi < 4; ++mi) a[mi] = rdA(buf, 1, mi + 4);
    __builtin_amdgcn_s_setprio(1);
#pragma unroll
    for (int mi = 0; mi < 4; ++mi)
#pragma unroll
      for (int ni = 0; ni < 4; ++ni)
        acc[mi + 4][ni] = __builtin_amdgcn_mfma_f32_16x16x32_bf16(a[mi], b[ni], acc[mi + 4][ni], 0, 0, 0);
    __builtin_amdgcn_s_setprio(0);
  }
}

// ---------------------------------------------------------------------------
// K0: fp32 -> bf16 cast
// ---------------------------------------------------------------------------
__global__ __launch_bounds__(256) void k_cvt(const float* __restrict__ s,
                                             short* __restrict__ d, int n4)
{
  int i  = blockIdx.x * blockDim.x + threadIdx.x;
  int st = gridDim.x * blockDim.x;
  for (; i < n4; i += st) {
    float4 v = ((const float4*)s)[i];
    s16x4 o = { f2bf(v.x), f2bf(v.y), f2bf(v.z), f2bf(v.w) };
    ((s16x4*)d)[i] = o;
  }
}

// ---------------------------------------------------------------------------
// K1: QKV projection. C[m=(t*B+b), e] = sum_d Qb[m,d]*W[h,e,d] + bias[h,e]
// grid (32, 2, 3*HG), 512 thr, 128 KiB dyn LDS, NT = 256/64 = 4
// ---------------------------------------------------------------------------
__global__ __launch_bounds__(512) void k_proj(
    const short* __restrict__ Qb,
    const short* __restrict__ Wqb, const short* __restrict__ Wkb, const short* __restrict__ Wvb,
    const float* __restrict__ bq, const float* __restrict__ bk, const float* __restrict__ bv,
    short* __restrict__ qb, short* __restrict__ kb, short* __restrict__ vb,
    int h0, int HG)
{
  extern __shared__ short lds[];
  const int bx = blockIdx.x, by = blockIdx.y, bz = blockIdx.z;
  const int p = bz / HG, hh = bz % HG, h = h0 + hh;

  const short* W    = (p == 0 ? Wqb : p == 1 ? Wkb : Wvb) + ((size_t)h * EH + (size_t)by * 256) * DIN;
  const float* bias = (p == 0 ? bq  : p == 1 ? bk  : bv ) + h * EH + by * 256;
  short* outp       = (p == 0 ? qb  : p == 1 ? kb  : vb ) + (size_t)hh * BATCH * T_SEQ * EH;
  const short* Ag   = Qb + (size_t)bx * 256 * DIN;

  f32x4_t acc[8][4] = {};
  gemm8p<DIN / 64>(Ag, DIN, W, DIN, lds, acc);

  const int lane = threadIdx.x & 63, wv = threadIdx.x >> 6;
  const int g = lane >> 4, r = lane & 15;
  const int Rw = (wv >> 2) * 128, Cw = (wv & 3) * 64;
#pragma unroll
  for (int ni = 0; ni < 4; ++ni) {
    int coll = Cw + ni * 16 + r;
    float bia = bias[coll];
    int e = by * 256 + coll;
#pragma unroll
    for (int mi = 0; mi < 8; ++mi) {
#pragma unroll
      for (int reg = 0; reg < 4; ++reg) {
        int m = bx * 256 + Rw + mi * 16 + g * 4 + reg;
        int t = m >> 3, b = m & 7;
        outp[((size_t)(b * T_SEQ + t)) * EH + e] = f2bf(acc[mi][ni][reg] + bia);
      }
    }
  }
}

// ---------------------------------------------------------------------------
// K3a: P[t,s] = exp(SCALE * q.k) bf16 + per-block column sums
// grid (4, 4, HG*8), 512 thr, NT = 512/64 = 8
// colpart[(z*4 + bx)*T + s] = sum over this block's 256 t of exp
// ---------------------------------------------------------------------------
__global__ __launch_bounds__(512) void k_pgen(
    const short* __restrict__ qb, const short* __restrict__ kb,
    short* __restrict__ Pbuf, float* __restrict__ colpart)
{
  extern __shared__ short lds[];
  const int bx = blockIdx.x, by = blockIdx.y, z = blockIdx.z;
  const short* Ag = qb + (size_t)z * T_SEQ * EH + (size_t)bx * 256 * EH;
  const short* Bg = kb + (size_t)z * T_SEQ * EH + (size_t)by * 256 * EH;

  f32x4_t acc[8][4] = {};
  gemm8p<EH / 64>(Ag, EH, Bg, EH, lds, acc);

  short* Pb = Pbuf + (size_t)z * T_SEQ * T_SEQ;
  const int lane = threadIdx.x & 63, wv = threadIdx.x >> 6;
  const int g = lane >> 4, r = lane & 15;
  const int Rw = (wv >> 2) * 128, Cw = (wv & 3) * 64;

  float cs[4] = {0.f, 0.f, 0.f, 0.f};
#pragma unroll
  for (int ni = 0; ni < 4; ++ni) {
    int s = by * 256 + Cw + ni * 16 + r;
#pragma unroll
    for (int mi = 0; mi < 8; ++mi) {
#pragma unroll
      for (int reg = 0; reg < 4; ++reg) {
        int t = bx * 256 + Rw + mi * 16 + g * 4 + reg;
        float ev = __expf(acc[mi][ni][reg] * SCALE);
        cs[ni] += ev;
        Pb[(size_t)t * T_SEQ + s] = f2bf(ev);
      }
    }
  }
  // reduce over g (rows) in-wave, then across wm via LDS.
  // csL lives in buf0; for even NT the last tile used buf1, and buf0's last
  // reads/writes completed before the peeled tile's P1 barrier -> safe.
#pragma unroll
  for (int ni = 0; ni < 4; ++ni) {
    cs[ni] += __shfl_xor(cs[ni], 16);
    cs[ni] += __shfl_xor(cs[ni], 32);
  }
  float* csL = (float*)lds;
  if (g == 0) {
#pragma unroll
    for (int ni = 0; ni < 4; ++ni) csL[(wv >> 2) * 256 + Cw + ni * 16 + r] = cs[ni];
  }
  __syncthreads();
  if (threadIdx.x < 256) {
    float tot = csL[threadIdx.x] + csL[256 + threadIdx.x];
    colpart[((size_t)z * 4 + bx) * T_SEQ + by * 256 + threadIdx.x] = tot;
  }
}

// ---------------------------------------------------------------------------
// K2': invs[z*T + s] = 1 / sum_tt colpart[(z*4+tt)*T + s]
// ---------------------------------------------------------------------------
__global__ __launch_bounds__(256) void k_invsum(const float* __restrict__ colpart,
                                                float* __restrict__ invs, int HB)
{
  int i = blockIdx.x * 256 + threadIdx.x;
  if (i < HB * T_SEQ) {
    int hb = i >> 10, s = i & (T_SEQ - 1);
    float sum = 0.f;
#pragma unroll
    for (int tt = 0; tt < 4; ++tt) sum += colpart[((size_t)hb * 4 + tt) * T_SEQ + s];
    invs[i] = 1.0f / sum;
  }
}

// ---------------------------------------------------------------------------
// K_tr: vbT[z][e][s] = vb[z][s][e] * invs[z][s]   (64x64 tiles via LDS)
// ---------------------------------------------------------------------------
__global__ __launch_bounds__(256) void k_tr(const short* __restrict__ vb,
                                            const float* __restrict__ invs,
                                            short* __restrict__ vbT)
{
  __shared__ float tl[64][65];
  const int bx = blockIdx.x, by = blockIdx.y, z = blockIdx.z;
  const short* in  = vb  + (size_t)z * T_SEQ * EH;
  short*       out = vbT + (size_t)z * EH * T_SEQ;
  const float* inv = invs + (size_t)z * T_SEQ;
  const int tid = threadIdx.x;

#pragma unroll
  for (int rep = 0; rep < 2; ++rep) {
    int s_l = (tid >> 3) + rep * 32;
    int e_l = (tid & 7) * 8;
    s16x8 v = *(const s16x8*)&in[(size_t)(bx * 64 + s_l) * EH + by * 64 + e_l];
    float iv = inv[bx * 64 + s_l];
#pragma unroll
    for (int j = 0; j < 8; ++j) tl[s_l][e_l + j] = bf2f(v[j]) * iv;
  }
  __syncthreads();
#pragma unroll
  for (int rep = 0; rep < 2; ++rep) {
    int e_w = (tid >> 3) + rep * 32;
    int s_w = (tid & 7) * 8;
    s16x8 o;
#pragma unroll
    for (int j = 0; j < 8; ++j) o[j] = f2bf(tl[s_w + j][e_w]);
    *(s16x8*)&out[(size_t)(by * 64 + e_w) * T_SEQ + bx * 64 + s_w] = o;
  }
}

// ---------------------------------------------------------------------------
// K3b: O[t,e] = sum_s P[t,s]*vbT[e,s] -> Hmat[t, b, h*EH + e] bf16
// grid (4, 2, HG*8), 512 thr, NT = 1024/64 = 16
// ---------------------------------------------------------------------------
__global__ __launch_bounds__(512) void k_ogemm(
    const short* __restrict__ Pbuf, const short* __restrict__ vbT,
    short* __restrict__ Hmat, int h0)
{
  extern __shared__ short lds[];
  const int bx = blockIdx.x, by = blockIdx.y, z = blockIdx.z;
  const short* Ag = Pbuf + (size_t)z * T_SEQ * T_SEQ + (size_t)bx * 256 * T_SEQ;
  const short* Bg = vbT  + (size_t)z * EH * T_SEQ    + (size_t)by * 256 * T_SEQ;

  f32x4_t acc[8][4] = {};
  gemm8p<T_SEQ / 64>(Ag, T_SEQ, Bg, T_SEQ, lds, acc);

  const int hh = z >> 3, b = z & 7, h = h0 + hh;
  const int lane = threadIdx.x & 63, wv = threadIdx.x >> 6;
  const int g = lane >> 4, r = lane & 15;
  const int Rw = (wv >> 2) * 128, Cw = (wv & 3) * 64;
#pragma unroll
  for (int ni = 0; ni < 4; ++ni) {
    int e = by * 256 + Cw + ni * 16 + r;
#pragma unroll
    for (int mi = 0; mi < 8; ++mi) {
#pragma unroll
      for (int reg = 0; reg < 4; ++reg) {
        int t = bx * 256 + Rw + mi * 16 + g * 4 + reg;
        Hmat[((size_t)t * BATCH + b) * HE + (size_t)h * EH + e] = f2bf(acc[mi][ni][reg]);
      }
    }
  }
}

// ---------------------------------------------------------------------------
// K4a: split-K output GEMM. part[ks][m][d] = sum_{he in ks-slice} Hmat*Wo
// grid (32, 1, 8 ks), 512 thr; each block K=512 (NT=8)
// ---------------------------------------------------------------------------
__global__ __launch_bounds__(512) void k_final(
    const short* __restrict__ Hmat, const short* __restrict__ Wob,
    float* __restrict__ part)
{
  extern __shared__ short lds[];
  const int bx = blockIdx.x, ks = blockIdx.z;
  const short* Ag = Hmat + (size_t)bx * 256 * HE + (size_t)ks * 512;
  const short* Bg = Wob  + (size_t)ks * 512;

  f32x4_t acc[8][4] = {};
  gemm8p<512 / 64>(Ag, HE, Bg, HE, lds, acc);

  float* pp = part + (size_t)ks * (T_SEQ * BATCH) * DIN;
  const int lane = threadIdx.x & 63, wv = threadIdx.x >> 6;
  const int g = lane >> 4, r = lane & 15;
  const int Rw = (wv >> 2) * 128, Cw = (wv & 3) * 64;
#pragma unroll
  for (int ni = 0; ni < 4; ++ni) {
    int d = Cw + ni * 16 + r;
#pragma unroll
    for (int mi = 0; mi < 8; ++mi) {
#pragma unroll
      for (int reg = 0; reg < 4; ++reg) {
        int m = bx * 256 + Rw + mi * 16 + g * 4 + reg;
        pp[(size_t)m * DIN + d] = acc[mi][ni][reg];
      }
    }
  }
}

// K4b: out[m,d] = sum_ks part + bo[d]
__global__ __launch_bounds__(256) void k_red(const float* __restrict__ part,
                                             const float* __restrict__ bo,
                                             float* __restrict__ out)
{
  int i = blockIdx.x * 256 + threadIdx.x;     // over 8192*256/4 float4s
  float4 s = ((const float4*)part)[i];
#pragma unroll
  for (int ks = 1; ks < 8; ++ks) {
    float4 p = ((const float4*)(part + (size_t)ks * T_SEQ * BATCH * DIN))[i];
    s.x += p.x; s.y += p.y; s.z += p.z; s.w += p.w;
  }
  float4 b4 = ((const float4*)bo)[i & 63];
  s.x += b4.x; s.y += b4.y; s.z += b4.z; s.w += b4.w;
  ((float4*)out)[i] = s;
}

// ---------------------------------------------------------------------------
extern "C" void kernel_launch(void* const* d_in, const int* in_sizes, int n_in,
                              void* d_out, int out_size, void* d_ws, size_t ws_size,
                              hipStream_t stream)
{
  const float* Q  = (const float*)d_in[0];
  const float* Wq = (const float*)d_in[1];
  const float* bq = (const float*)d_in[2];
  const float* Wk = (const float*)d_in[3];
  const float* bk = (const float*)d_in[4];
  const float* Wv = (const float*)d_in[5];
  const float* bv = (const float*)d_in[6];
  const float* Wo = (const float*)d_in[7];
  const float* bo = (const float*)d_in[8];
  float* out = (float*)d_out;

  // opt into 128 KiB dynamic LDS for the 8-wave GEMM kernels (idempotent)
  (void)hipFuncSetAttribute((const void*)k_proj,  hipFuncAttributeMaxDynamicSharedMemorySize, 131072);
  (void)hipFuncSetAttribute((const void*)k_pgen,  hipFuncAttributeMaxDynamicSharedMemorySize, 131072);
  (void)hipFuncSetAttribute((const void*)k_ogemm, hipFuncAttributeMaxDynamicSharedMemorySize, 131072);
  (void)hipFuncSetAttribute((const void*)k_final, hipFuncAttributeMaxDynamicSharedMemorySize, 131072);

  // ---- workspace layout (bump allocator, 256B aligned) ----
  const size_t QB_B   = (size_t)T_SEQ * BATCH * DIN * 2;          //   4 MiB
  const size_t W_B    = (size_t)NH * EH * DIN * 2;                //   2 MiB each
  const size_t WO_B   = (size_t)DIN * HE * 2;                     //   2 MiB
  const size_t HMAT_B = (size_t)T_SEQ * BATCH * HE * 2;           //  64 MiB
  const size_t PART_B = (size_t)8 * T_SEQ * BATCH * DIN * 4;      //  64 MiB
  const size_t QKV_B  = (size_t)BATCH * T_SEQ * EH * 2;           //   8 MiB / head
  const size_t P_B    = (size_t)BATCH * T_SEQ * T_SEQ * 2;        //  16 MiB / head
  const size_t INV_B  = (size_t)BATCH * T_SEQ * 4;
  const size_t CP_B   = (size_t)BATCH * 4 * T_SEQ * 4;

  const size_t fixedB  = QB_B + 3 * W_B + WO_B + HMAT_B + PART_B;
  const size_t perHead = 4 * QKV_B + P_B + INV_B + CP_B;

  int HG = 8;
  while (HG > 1 && fixedB + (size_t)HG * perHead + 65536 > ws_size) HG >>= 1;

  char* w = (char*)d_ws;
  auto alloc = [&](size_t bytes) {
    char* p = w;
    w += (bytes + 255) & ~(size_t)255;
    return p;
  };
  short* Qb   = (short*)alloc(QB_B);
  short* Wqb  = (short*)alloc(W_B);
  short* Wkb  = (short*)alloc(W_B);
  short* Wvb  = (short*)alloc(W_B);
  short* Wob  = (short*)alloc(WO_B);
  short* Hmat = (short*)alloc(HMAT_B);
  float* part = (float*)alloc(PART_B);
  short* qb   = (short*)alloc((size_t)HG * QKV_B);
  short* kb   = (short*)alloc((size_t)HG * QKV_B);
  short* vb   = (short*)alloc((size_t)HG * QKV_B);
  short* vbT  = (short*)alloc((size_t)HG * QKV_B);
  short* Pbuf = (short*)alloc((size_t)HG * P_B);
  float* invs = (float*)alloc((size_t)HG * INV_B);
  float* cpart= (float*)alloc((size_t)HG * CP_B);

  // ---- casts ----
  k_cvt<<<dim3(2048), 256, 0, stream>>>(Q,  Qb,  T_SEQ * BATCH * DIN / 4);
  k_cvt<<<dim3(1024), 256, 0, stream>>>(Wq, Wqb, NH * EH * DIN / 4);
  k_cvt<<<dim3(1024), 256, 0, stream>>>(Wk, Wkb, NH * EH * DIN / 4);
  k_cvt<<<dim3(1024), 256, 0, stream>>>(Wv, Wvb, NH * EH * DIN / 4);
  k_cvt<<<dim3(1024), 256, 0, stream>>>(Wo, Wob, DIN * HE / 4);

  for (int h0 = 0; h0 < NH; h0 += HG) {
    k_proj  <<<dim3(32, 2, 3 * HG), 512, 131072, stream>>>(Qb, Wqb, Wkb, Wvb, bq, bk, bv,
                                                           qb, kb, vb, h0, HG);
    k_pgen  <<<dim3(4, 4, HG * BATCH), 512, 131072, stream>>>(qb, kb, Pbuf, cpart);
    k_invsum<<<dim3(HG * BATCH * T_SEQ / 256), 256, 0, stream>>>(cpart, invs, HG * BATCH);
    k_tr    <<<dim3(16, 8, HG * BATCH), 256, 0, stream>>>(vb, invs, vbT);
    k_ogemm <<<dim3(4, 2, HG * BATCH), 512, 131072, stream>>>(Pbuf, vbT, Hmat, h0);
  }
  k_final<<<dim3(32, 1, 8), 512, 131072, stream>>>(Hmat, Wob, part);
  k_red  <<<dim3(T_SEQ * BATCH * DIN / 4 / 256), 256, 0, stream>>>(part, bo, out);
}

// Round 4
// 422.804 us; speedup vs baseline: 1.1615x; 1.1615x over previous
//
#include <hip/hip_runtime.h>
#include <stdint.h>
#include <stddef.h>

// Problem constants (MultiHeadAttention_52759378264454)
constexpr int T_SEQ = 1024;
constexpr int BATCH = 8;
constexpr int DIN   = 256;
constexpr int NH    = 8;
constexpr int EH    = 512;
constexpr int HE    = NH * EH;   // 4096
constexpr float SCALE = 0.044194173824159216f; // 1/sqrt(512)

typedef __attribute__((ext_vector_type(8))) short s16x8;
typedef __attribute__((ext_vector_type(4))) short s16x4;
typedef __attribute__((ext_vector_type(4))) float f32x4_t;

__device__ __forceinline__ short f2bf(float f) {
  union { float f; uint32_t u; } c; c.f = f;
  uint32_t u = c.u;
  u += 0x7fffu + ((u >> 16) & 1u);   // RNE (finite values only here)
  return (short)(u >> 16);
}
__device__ __forceinline__ float bf2f(short s) {
  union { uint32_t u; float f; } c; c.u = ((uint32_t)(uint16_t)s) << 16;
  return c.f;
}

// async global->LDS, 16B per lane. LDS dest = wave-uniform base + lane*16 (HW).
__device__ __forceinline__ void gload16(const short* g, short* l) {
  __builtin_amdgcn_global_load_lds(
      (__attribute__((address_space(1))) void*)(void*)const_cast<short*>(g),
      (__attribute__((address_space(3))) void*)(void*)l, 16, 0, 0);
}

#define BAR_FENCE do { __builtin_amdgcn_s_barrier(); asm volatile("" ::: "memory"); } while (0)
#define WAITVM(N) asm volatile("s_waitcnt vmcnt(" #N ")" ::: "memory")

// ---------------------------------------------------------------------------
// 8-wave 256x256 GEMM, BK=64, double-buffered LDS (128 KiB), 4-phase/K-tile
// schedule with counted vmcnt (T2+T3+T4+T5). See round-3 ledger comments.
// ---------------------------------------------------------------------------
template<int NT>   // K = NT*64, NT >= 2, NT even
__device__ __forceinline__ void gemm8p(const short* __restrict__ Ag, int lda,
                                       const short* __restrict__ Bg, int ldb,
                                       short* lds, f32x4_t (&acc)[8][4])
{
  const int tid  = threadIdx.x;
  const int lane = tid & 63, wv = tid >> 6;
  const int r = lane & 15, g = lane >> 4;
  const int Rw = (wv >> 2) * 128, Cw = (wv & 3) * 64;
  // read-side swizzled chunk offset (shorts)
  const int cpS = (g ^ (r & 3) ^ ((r >> 2) & 3)) * 8;

  // stage-side: load j covers chunk d = tid + j*512 of a 1024-chunk half
  int s_row[2], s_col[2], dstc[2];
#pragma unroll
  for (int j = 0; j < 2; ++j) {
    int d = tid + j * 512;
    int row = d >> 2, cp = d & 3;
    s_row[j] = row;
    s_col[j] = (cp ^ (row & 3) ^ ((row >> 2) & 3)) * 8;   // source chunk (involution)
    dstc[j]  = (wv * 64 + j * 512) * 8;                   // wave-uniform LDS base
  }

  auto stageA = [&](int t, int h) {
    short* base = lds + (t & 1) * 32768 + h * 8192;
#pragma unroll
    for (int j = 0; j < 2; ++j)
      gload16(Ag + (size_t)s_row[j] * lda + t * 64 + h * 32 + s_col[j], base + dstc[j]);
  };
  auto stageB = [&](int t, int h) {
    short* base = lds + (t & 1) * 32768 + 16384 + h * 8192;
#pragma unroll
    for (int j = 0; j < 2; ++j)
      gload16(Bg + (size_t)s_row[j] * ldb + t * 64 + h * 32 + s_col[j], base + dstc[j]);
  };
  auto rdA = [&](const short* buf, int h, int mi) -> s16x8 {
    return *(const s16x8*)(buf + h * 8192 + (Rw + mi * 16 + r) * 32 + cpS);
  };
  auto rdB = [&](const short* buf, int h, int ni) -> s16x8 {
    return *(const s16x8*)(buf + 16384 + h * 8192 + (Cw + ni * 16 + r) * 32 + cpS);
  };

  // prologue: tile0 complete + tile1 h0 halves (12 loads in flight)
  stageA(0, 0); stageB(0, 0); stageA(0, 1); stageB(0, 1);
  stageA(1, 0); stageB(1, 0);

  s16x8 a[4], b[4];
#pragma unroll 1
  for (int t = 0; t < NT; ++t) {
    const short* buf = lds + (t & 1) * 32768;
    const bool last = (t == NT - 1);
    // ---------------- P1 ----------------
    if (last) { WAITVM(4); } else { WAITVM(8); }
    BAR_FENCE;
    if (t + 1 < NT) stageA(t + 1, 1);
#pragma unroll
    for (int ni = 0; ni < 4; ++ni) b[ni] = rdB(buf, 0, ni);
#pragma unroll
    for (int mi = 0; mi < 4; ++mi) a[mi] = rdA(buf, 0, mi);
    __builtin_amdgcn_s_setprio(1);
#pragma unroll
    for (int mi = 0; mi < 4; ++mi)
#pragma unroll
      for (int ni = 0; ni < 4; ++ni)
        acc[mi][ni] = __builtin_amdgcn_mfma_f32_16x16x32_bf16(a[mi], b[ni], acc[mi][ni], 0, 0, 0);
    __builtin_amdgcn_s_setprio(0);
    // ---------------- P2 ----------------
    if (t + 1 < NT) stageB(t + 1, 1);
#pragma unroll
    for (int mi = 0; mi < 4; ++mi) a[mi] = rdA(buf, 0, mi + 4);
    __builtin_amdgcn_s_setprio(1);
#pragma unroll
    for (int mi = 0; mi < 4; ++mi)
#pragma unroll
      for (int ni = 0; ni < 4; ++ni)
        acc[mi + 4][ni] = __builtin_amdgcn_mfma_f32_16x16x32_bf16(a[mi], b[ni], acc[mi + 4][ni], 0, 0, 0);
    __builtin_amdgcn_s_setprio(0);
    // ---------------- P3 ----------------
    if (last) { WAITVM(0); } else { WAITVM(8); }
    BAR_FENCE;
    if (t + 2 < NT) stageA(t + 2, 0);
#pragma unroll
    for (int ni = 0; ni < 4; ++ni) b[ni] = rdB(buf, 1, ni);
#pragma unroll
    for (int mi = 0; mi < 4; ++mi) a[mi] = rdA(buf, 1, mi);
    __builtin_amdgcn_s_setprio(1);
#pragma unroll
    for (int mi = 0; mi < 4; ++mi)
#pragma unroll
      for (int ni = 0; ni < 4; ++ni)
        acc[mi][ni] = __builtin_amdgcn_mfma_f32_16x16x32_bf16(a[mi], b[ni], acc[mi][ni], 0, 0, 0);
    __builtin_amdgcn_s_setprio(0);
    // ---------------- P4 ----------------
    if (t + 2 < NT) stageB(t + 2, 0);
#pragma unroll
    for (int mi = 0; mi < 4; ++mi) a[mi] = rdA(buf, 1, mi + 4);
    __builtin_amdgcn_s_setprio(1);
#pragma unroll
    for (int mi = 0; mi < 4; ++mi)
#pragma unroll
      for (int ni = 0; ni < 4; ++ni)
        acc[mi + 4][ni] = __builtin_amdgcn_mfma_f32_16x16x32_bf16(a[mi], b[ni], acc[mi + 4][ni], 0, 0, 0);
    __builtin_amdgcn_s_setprio(0);
  }
}

// ---------------------------------------------------------------------------
// K0: fused fp32->bf16 cast of all five inputs into one CONTIGUOUS dst arena
// (Qb | Wqb | Wkb | Wvb | Wob). Sizes in float4 units.
// ---------------------------------------------------------------------------
__global__ __launch_bounds__(256) void k_cvt_all(
    const float* __restrict__ Q,  const float* __restrict__ Wq,
    const float* __restrict__ Wk, const float* __restrict__ Wv,
    const float* __restrict__ Wo, short* __restrict__ dst)
{
  constexpr int N_Q = 524288;              // 1024*8*256/4
  constexpr int N_W = 262144;              // 8*512*256/4
  constexpr int TOT = N_Q + 4 * N_W;       // 1572864
  int i  = blockIdx.x * 256 + threadIdx.x;
  int st = gridDim.x * 256;
  for (; i < TOT; i += st) {
    const float* s; int off;
    if (i < N_Q)                { s = Q;  off = i; }
    else if (i < N_Q + N_W)     { s = Wq; off = i - N_Q; }
    else if (i < N_Q + 2 * N_W) { s = Wk; off = i - N_Q - N_W; }
    else if (i < N_Q + 3 * N_W) { s = Wv; off = i - N_Q - 2 * N_W; }
    else                        { s = Wo; off = i - N_Q - 3 * N_W; }
    float4 v = ((const float4*)s)[off];
    s16x4 o = { f2bf(v.x), f2bf(v.y), f2bf(v.z), f2bf(v.w) };
    ((s16x4*)dst)[i] = o;
  }
}

// ---------------------------------------------------------------------------
// K1: QKV projection. C[m=(t*B+b), e] = sum_d Qb[m,d]*W[h,e,d] + bias[h,e]
// grid (32, 2, 3*HG), 512 thr, 128 KiB dyn LDS, NT = 256/64 = 4
// ---------------------------------------------------------------------------
__global__ __launch_bounds__(512) void k_proj(
    const short* __restrict__ Qb,
    const short* __restrict__ Wqb, const short* __restrict__ Wkb, const short* __restrict__ Wvb,
    const float* __restrict__ bq, const float* __restrict__ bk, const float* __restrict__ bv,
    short* __restrict__ qb, short* __restrict__ kb, short* __restrict__ vb,
    int h0, int HG)
{
  extern __shared__ short lds[];
  const int bx = blockIdx.x, by = blockIdx.y, bz = blockIdx.z;
  const int p = bz / HG, hh = bz % HG, h = h0 + hh;

  const short* W    = (p == 0 ? Wqb : p == 1 ? Wkb : Wvb) + ((size_t)h * EH + (size_t)by * 256) * DIN;
  const float* bias = (p == 0 ? bq  : p == 1 ? bk  : bv ) + h * EH + by * 256;
  short* outp       = (p == 0 ? qb  : p == 1 ? kb  : vb ) + (size_t)hh * BATCH * T_SEQ * EH;
  const short* Ag   = Qb + (size_t)bx * 256 * DIN;

  f32x4_t acc[8][4] = {};
  gemm8p<DIN / 64>(Ag, DIN, W, DIN, lds, acc);

  const int lane = threadIdx.x & 63, wv = threadIdx.x >> 6;
  const int g = lane >> 4, r = lane & 15;
  const int Rw = (wv >> 2) * 128, Cw = (wv & 3) * 64;
#pragma unroll
  for (int ni = 0; ni < 4; ++ni) {
    int coll = Cw + ni * 16 + r;
    float bia = bias[coll];
    int e = by * 256 + coll;
#pragma unroll
    for (int mi = 0; mi < 8; ++mi) {
#pragma unroll
      for (int reg = 0; reg < 4; ++reg) {
        int m = bx * 256 + Rw + mi * 16 + g * 4 + reg;
        int t = m >> 3, b = m & 7;
        outp[((size_t)(b * T_SEQ + t)) * EH + e] = f2bf(acc[mi][ni][reg] + bia);
      }
    }
  }
}

// ---------------------------------------------------------------------------
// K3a: P[t,s] = exp(SCALE * q.k) bf16 + per-block column sums
// grid (4, 4, HG*8), 512 thr, NT = 512/64 = 8
// colpart[(z*4 + bx)*T + s] = sum over this block's 256 t of exp
// ---------------------------------------------------------------------------
__global__ __launch_bounds__(512) void k_pgen(
    const short* __restrict__ qb, const short* __restrict__ kb,
    short* __restrict__ Pbuf, float* __restrict__ colpart)
{
  extern __shared__ short lds[];
  const int bx = blockIdx.x, by = blockIdx.y, z = blockIdx.z;
  const short* Ag = qb + (size_t)z * T_SEQ * EH + (size_t)bx * 256 * EH;
  const short* Bg = kb + (size_t)z * T_SEQ * EH + (size_t)by * 256 * EH;

  f32x4_t acc[8][4] = {};
  gemm8p<EH / 64>(Ag, EH, Bg, EH, lds, acc);

  short* Pb = Pbuf + (size_t)z * T_SEQ * T_SEQ;
  const int lane = threadIdx.x & 63, wv = threadIdx.x >> 6;
  const int g = lane >> 4, r = lane & 15;
  const int Rw = (wv >> 2) * 128, Cw = (wv & 3) * 64;

  float cs[4] = {0.f, 0.f, 0.f, 0.f};
#pragma unroll
  for (int ni = 0; ni < 4; ++ni) {
    int s = by * 256 + Cw + ni * 16 + r;
#pragma unroll
    for (int mi = 0; mi < 8; ++mi) {
#pragma unroll
      for (int reg = 0; reg < 4; ++reg) {
        int t = bx * 256 + Rw + mi * 16 + g * 4 + reg;
        float ev = __expf(acc[mi][ni][reg] * SCALE);
        cs[ni] += ev;
        Pb[(size_t)t * T_SEQ + s] = f2bf(ev);
      }
    }
  }
  // reduce over g (rows) in-wave, then across wm via LDS (safe after last tile)
#pragma unroll
  for (int ni = 0; ni < 4; ++ni) {
    cs[ni] += __shfl_xor(cs[ni], 16);
    cs[ni] += __shfl_xor(cs[ni], 32);
  }
  float* csL = (float*)lds;
  if (g == 0) {
#pragma unroll
    for (int ni = 0; ni < 4; ++ni) csL[(wv >> 2) * 256 + Cw + ni * 16 + r] = cs[ni];
  }
  __syncthreads();
  if (threadIdx.x < 256) {
    float tot = csL[threadIdx.x] + csL[256 + threadIdx.x];
    colpart[((size_t)z * 4 + bx) * T_SEQ + by * 256 + threadIdx.x] = tot;
  }
}

// ---------------------------------------------------------------------------
// K_tr (+fused invsum): vbT[z][e][s] = vb[z][s][e] / colsum[z][s]
// grid (16, 8, HG*8); inv computed in-block from colpart (4 partials per s)
// ---------------------------------------------------------------------------
__global__ __launch_bounds__(256) void k_tr(const short* __restrict__ vb,
                                            const float* __restrict__ colpart,
                                            short* __restrict__ vbT)
{
  __shared__ float tl[64][65];
  __shared__ float invL[64];
  const int bx = blockIdx.x, by = blockIdx.y, z = blockIdx.z;
  const short* in  = vb  + (size_t)z * T_SEQ * EH;
  short*       out = vbT + (size_t)z * EH * T_SEQ;
  const int tid = threadIdx.x;

  if (tid < 64) {
    int s = bx * 64 + tid;
    float sum = 0.f;
#pragma unroll
    for (int tt = 0; tt < 4; ++tt) sum += colpart[((size_t)z * 4 + tt) * T_SEQ + s];
    invL[tid] = 1.0f / sum;
  }
  __syncthreads();

#pragma unroll
  for (int rep = 0; rep < 2; ++rep) {
    int s_l = (tid >> 3) + rep * 32;
    int e_l = (tid & 7) * 8;
    s16x8 v = *(const s16x8*)&in[(size_t)(bx * 64 + s_l) * EH + by * 64 + e_l];
    float iv = invL[s_l];
#pragma unroll
    for (int j = 0; j < 8; ++j) tl[s_l][e_l + j] = bf2f(v[j]) * iv;
  }
  __syncthreads();
#pragma unroll
  for (int rep = 0; rep < 2; ++rep) {
    int e_w = (tid >> 3) + rep * 32;
    int s_w = (tid & 7) * 8;
    s16x8 o;
#pragma unroll
    for (int j = 0; j < 8; ++j) o[j] = f2bf(tl[s_w + j][e_w]);
    *(s16x8*)&out[(size_t)(by * 64 + e_w) * T_SEQ + bx * 64 + s_w] = o;
  }
}

// ---------------------------------------------------------------------------
// K3b: O[t,e] = sum_s P[t,s]*vbT[e,s] -> Hmat[t, b, h*EH + e] bf16
// grid (4, 2, HG*8), 512 thr, NT = 1024/64 = 16
// ---------------------------------------------------------------------------
__global__ __launch_bounds__(512) void k_ogemm(
    const short* __restrict__ Pbuf, const short* __restrict__ vbT,
    short* __restrict__ Hmat, int h0)
{
  extern __shared__ short lds[];
  const int bx = blockIdx.x, by = blockIdx.y, z = blockIdx.z;
  const short* Ag = Pbuf + (size_t)z * T_SEQ * T_SEQ + (size_t)bx * 256 * T_SEQ;
  const short* Bg = vbT  + (size_t)z * EH * T_SEQ    + (size_t)by * 256 * T_SEQ;

  f32x4_t acc[8][4] = {};
  gemm8p<T_SEQ / 64>(Ag, T_SEQ, Bg, T_SEQ, lds, acc);

  const int hh = z >> 3, b = z & 7, h = h0 + hh;
  const int lane = threadIdx.x & 63, wv = threadIdx.x >> 6;
  const int g = lane >> 4, r = lane & 15;
  const int Rw = (wv >> 2) * 128, Cw = (wv & 3) * 64;
#pragma unroll
  for (int ni = 0; ni < 4; ++ni) {
    int e = by * 256 + Cw + ni * 16 + r;
#pragma unroll
    for (int mi = 0; mi < 8; ++mi) {
#pragma unroll
      for (int reg = 0; reg < 4; ++reg) {
        int t = bx * 256 + Rw + mi * 16 + g * 4 + reg;
        Hmat[((size_t)t * BATCH + b) * HE + (size_t)h * EH + e] = f2bf(acc[mi][ni][reg]);
      }
    }
  }
}

// ---------------------------------------------------------------------------
// K4a: split-K output GEMM. part[ks][m][d] = sum_{he in ks-slice} Hmat*Wo
// grid (32, 1, 8 ks), 512 thr; each block K=512 (NT=8)
// ---------------------------------------------------------------------------
__global__ __launch_bounds__(512) void k_final(
    const short* __restrict__ Hmat, const short* __restrict__ Wob,
    float* __restrict__ part)
{
  extern __shared__ short lds[];
  const int bx = blockIdx.x, ks = blockIdx.z;
  const short* Ag = Hmat + (size_t)bx * 256 * HE + (size_t)ks * 512;
  const short* Bg = Wob  + (size_t)ks * 512;

  f32x4_t acc[8][4] = {};
  gemm8p<512 / 64>(Ag, HE, Bg, HE, lds, acc);

  float* pp = part + (size_t)ks * (T_SEQ * BATCH) * DIN;
  const int lane = threadIdx.x & 63, wv = threadIdx.x >> 6;
  const int g = lane >> 4, r = lane & 15;
  const int Rw = (wv >> 2) * 128, Cw = (wv & 3) * 64;
#pragma unroll
  for (int ni = 0; ni < 4; ++ni) {
    int d = Cw + ni * 16 + r;
#pragma unroll
    for (int mi = 0; mi < 8; ++mi) {
#pragma unroll
      for (int reg = 0; reg < 4; ++reg) {
        int m = bx * 256 + Rw + mi * 16 + g * 4 + reg;
        pp[(size_t)m * DIN + d] = acc[mi][ni][reg];
      }
    }
  }
}

// K4b: out[m,d] = sum_ks part + bo[d]
__global__ __launch_bounds__(256) void k_red(const float* __restrict__ part,
                                             const float* __restrict__ bo,
                                             float* __restrict__ out)
{
  int i = blockIdx.x * 256 + threadIdx.x;     // over 8192*256/4 float4s
  float4 s = ((const float4*)part)[i];
#pragma unroll
  for (int ks = 1; ks < 8; ++ks) {
    float4 p = ((const float4*)(part + (size_t)ks * T_SEQ * BATCH * DIN))[i];
    s.x += p.x; s.y += p.y; s.z += p.z; s.w += p.w;
  }
  float4 b4 = ((const float4*)bo)[i & 63];
  s.x += b4.x; s.y += b4.y; s.z += b4.z; s.w += b4.w;
  ((float4*)out)[i] = s;
}

// ---------------------------------------------------------------------------
extern "C" void kernel_launch(void* const* d_in, const int* in_sizes, int n_in,
                              void* d_out, int out_size, void* d_ws, size_t ws_size,
                              hipStream_t stream)
{
  const float* Q  = (const float*)d_in[0];
  const float* Wq = (const float*)d_in[1];
  const float* bq = (const float*)d_in[2];
  const float* Wk = (const float*)d_in[3];
  const float* bk = (const float*)d_in[4];
  const float* Wv = (const float*)d_in[5];
  const float* bv = (const float*)d_in[6];
  const float* Wo = (const float*)d_in[7];
  const float* bo = (const float*)d_in[8];
  float* out = (float*)d_out;

  // opt into 128 KiB dynamic LDS for the 8-wave GEMM kernels (idempotent)
  (void)hipFuncSetAttribute((const void*)k_proj,  hipFuncAttributeMaxDynamicSharedMemorySize, 131072);
  (void)hipFuncSetAttribute((const void*)k_pgen,  hipFuncAttributeMaxDynamicSharedMemorySize, 131072);
  (void)hipFuncSetAttribute((const void*)k_ogemm, hipFuncAttributeMaxDynamicSharedMemorySize, 131072);
  (void)hipFuncSetAttribute((const void*)k_final, hipFuncAttributeMaxDynamicSharedMemorySize, 131072);

  // ---- sizes ----
  const size_t QB_B   = (size_t)T_SEQ * BATCH * DIN * 2;       //  4 MiB
  const size_t W_B    = (size_t)NH * EH * DIN * 2;             //  2 MiB each
  const size_t WO_B   = (size_t)DIN * HE * 2;                  //  2 MiB
  const size_t HMAT_B = (size_t)T_SEQ * BATCH * HE * 2;        // 64 MiB
  const size_t PART_B = (size_t)8 * T_SEQ * BATCH * DIN * 4;   // 64 MiB
  const size_t QKV1   = (size_t)BATCH * T_SEQ * EH * 2;        //  8 MiB / head
  const size_t P1     = (size_t)BATCH * T_SEQ * T_SEQ * 2;     // 16 MiB / head
  const size_t CP1    = (size_t)BATCH * 4 * T_SEQ * 4;         // 128 KiB / head
  const size_t inputsB = QB_B + 3 * W_B + WO_B;                // 12 MiB (contiguous!)

  // ---- pick largest HG whose ALIASED plan fits ws_size ----
  // aliases: vbT <-> qb (same size); part <-> P-share region (max of the two)
  int HG = 8;
  for (; HG > 1; HG >>= 1) {
    size_t share = ((size_t)HG * P1 > PART_B) ? (size_t)HG * P1 : PART_B;
    size_t tot = inputsB + 3 * (size_t)HG * QKV1 + share + HMAT_B
               + (size_t)HG * CP1 + 8192;
    if (tot <= ws_size) break;
  }
  size_t shareB = ((size_t)HG * P1 > PART_B) ? (size_t)HG * P1 : PART_B;

  char* w = (char*)d_ws;
  auto alloc = [&](size_t bytes) {
    char* p = w;
    w += (bytes + 255) & ~(size_t)255;
    return p;
  };
  // contiguous cast arena (k_cvt_all writes Qb..Wob in one pass)
  short* Qb   = (short*)alloc(QB_B);
  short* Wqb  = (short*)alloc(W_B);
  short* Wkb  = (short*)alloc(W_B);
  short* Wvb  = (short*)alloc(W_B);
  short* Wob  = (short*)alloc(WO_B);
  float* cpart= (float*)alloc((size_t)HG * CP1);
  short* qb   = (short*)alloc((size_t)HG * QKV1);   // aliased by vbT after pgen
  short* kb   = (short*)alloc((size_t)HG * QKV1);
  short* vb   = (short*)alloc((size_t)HG * QKV1);
  char*  shr  = alloc(shareB);                      // P during loop; part after
  short* Hmat = (short*)alloc(HMAT_B);

  short* vbT  = qb;              // alias: qb dead after k_pgen, tr after pgen
  short* Pbuf = (short*)shr;     // alias: P dead after last k_ogemm
  float* part = (float*)shr;     // k_final runs after the loop

  // ---- K0: fused casts (one kernel) ----
  k_cvt_all<<<dim3(2048), 256, 0, stream>>>(Q, Wq, Wk, Wv, Wo, Qb);

  for (int h0 = 0; h0 < NH; h0 += HG) {
    k_proj <<<dim3(32, 2, 3 * HG),  512, 131072, stream>>>(Qb, Wqb, Wkb, Wvb, bq, bk, bv,
                                                           qb, kb, vb, h0, HG);
    k_pgen <<<dim3(4, 4, HG * BATCH), 512, 131072, stream>>>(qb, kb, Pbuf, cpart);
    k_tr   <<<dim3(16, 8, HG * BATCH), 256, 0, stream>>>(vb, cpart, vbT);
    k_ogemm<<<dim3(4, 2, HG * BATCH), 512, 131072, stream>>>(Pbuf, vbT, Hmat, h0);
  }
  k_final<<<dim3(32, 1, 8), 512, 131072, stream>>>(Hmat, Wob, part);
  k_red  <<<dim3(T_SEQ * BATCH * DIN / 4 / 256), 256, 0, stream>>>(part, bo, out);
}

// Round 5
// 356.946 us; speedup vs baseline: 1.3758x; 1.1845x over previous
//
#include <hip/hip_runtime.h>
#include <stdint.h>
#include <stddef.h>

// Problem constants (MultiHeadAttention_52759378264454)
constexpr int T_SEQ = 1024;
constexpr int BATCH = 8;
constexpr int DIN   = 256;
constexpr int NH    = 8;
constexpr int EH    = 512;
constexpr int HE    = NH * EH;   // 4096
constexpr float SCALE = 0.044194173824159216f; // 1/sqrt(512)

typedef __attribute__((ext_vector_type(8)))  short s16x8;
typedef __attribute__((ext_vector_type(4)))  short s16x4;
typedef __attribute__((ext_vector_type(16))) float f32x16;

__device__ __forceinline__ short f2bf(float f) {
  union { float f; uint32_t u; } c; c.f = f;
  uint32_t u = c.u;
  u += 0x7fffu + ((u >> 16) & 1u);   // RNE
  return (short)(u >> 16);
}
__device__ __forceinline__ float bf2f(short s) {
  union { uint32_t u; float f; } c; c.u = ((uint32_t)(uint16_t)s) << 16;
  return c.f;
}

// async global->LDS, 16B/lane. LDS dest = wave-uniform base + lane*16 (HW).
__device__ __forceinline__ void gload16(const short* g, short* l) {
  __builtin_amdgcn_global_load_lds(
      (__attribute__((address_space(1))) void*)(void*)const_cast<short*>(g),
      (__attribute__((address_space(3))) void*)(void*)l, 16, 0, 0);
}

#define WAITVM(N) asm volatile("s_waitcnt vmcnt(" #N ")" ::: "memory")
#define BARF do { asm volatile("" ::: "memory"); __builtin_amdgcn_s_barrier(); \
                  asm volatile("" ::: "memory"); } while (0)

// ---------------------------------------------------------------------------
// 8-wave 256x128 GEMM, BK=32, mfma_f32_32x32x16_bf16, double-buffered 48 KiB
// LDS, counted vmcnt (steady-state vmcnt(3), tile t+2 always in flight).
// C[256,128] += A[256,K] * B[128,K]^T, A/B K-major bf16.
// Waves: wm = wv>>1 (4), wn = wv&1 (2); per-wave 64x64 = 2mi x 2ni of 32x32.
// LDS slot (24 KiB): A[256][32] at 0, B[128][32] at 8192 (shorts).
// Swizzle: 16B chunk cp within 64B row: cp ^= (row&3)^((row>>2)&3), applied on
// pre-swizzled global source AND on read (involution, both-sides - rule 21).
// A-frag (32x32x16): lane l: row=l&31, k=(l>>5)*8+j ; C/D: col=l&31,
// row=(reg&3)+8*(reg>>2)+4*(l>>5)  [guide m74/m101].
// Schedule/K-tile: {waitvm; bar; [kk=0: 4 ds_read, 4 MFMA][kk=1: same];
//                   bar; stage(t+2)}  -> WAR-safe: stage after all reads done.
// ---------------------------------------------------------------------------
template<int NT>   // K = NT*32, NT >= 2
__device__ __forceinline__ void gemm32(const short* __restrict__ Ag, int lda,
                                       const short* __restrict__ Bg, int ldb,
                                       short* lds, f32x16 (&acc)[2][2])
{
  const int tid = threadIdx.x;
  const int l   = tid & 63, wv = tid >> 6;
  const int hi  = l >> 5;
  const int Rw  = (wv >> 1) * 64, Cw = (wv & 1) * 64;
  const int fl  = (l & 3) ^ ((l >> 2) & 3);

  int oA[2][2], oB[2][2];
#pragma unroll
  for (int kk = 0; kk < 2; ++kk) {
    int cp = (((kk << 1) | hi) ^ fl) * 8;
#pragma unroll
    for (int mi = 0; mi < 2; ++mi) oA[kk][mi] = (Rw + mi * 32 + (l & 31)) * 32 + cp;
#pragma unroll
    for (int ni = 0; ni < 2; ++ni) oB[kk][ni] = 8192 + (Cw + ni * 32 + (l & 31)) * 32 + cp;
  }

  // stage-side: A = 1024 chunks (2/thread), B = 512 chunks (1/thread)
  const int rA0 = tid >> 2;
  const int sA0 = ((tid & 3) ^ ((rA0 & 3) ^ ((rA0 >> 2) & 3))) * 8;
  const int cA1 = tid + 512, rA1 = cA1 >> 2;
  const int sA1 = ((cA1 & 3) ^ ((rA1 & 3) ^ ((rA1 >> 2) & 3))) * 8;
  const int rB0 = tid >> 2;
  const int sB0 = ((tid & 3) ^ ((rB0 & 3) ^ ((rB0 >> 2) & 3))) * 8;
  const int dA0 = (wv * 64) * 8, dA1 = (wv * 64 + 512) * 8, dB0 = 8192 + (wv * 64) * 8;

  auto stage = [&](int t) {
    short* slot = lds + (t & 1) * 12288;
    const int ko = t * 32;
    gload16(Ag + (size_t)rA0 * lda + ko + sA0, slot + dA0);
    gload16(Ag + (size_t)rA1 * lda + ko + sA1, slot + dA1);
    gload16(Bg + (size_t)rB0 * ldb + ko + sB0, slot + dB0);
  };

  stage(0); stage(1);   // 6 loads in flight

#pragma unroll 1
  for (int t = 0; t < NT; ++t) {
    const short* buf = lds + (t & 1) * 12288;
    if (t == NT - 1) { WAITVM(0); } else { WAITVM(3); }
    BARF;
#pragma unroll
    for (int kk = 0; kk < 2; ++kk) {
      s16x8 a0 = *(const s16x8*)(buf + oA[kk][0]);
      s16x8 a1 = *(const s16x8*)(buf + oA[kk][1]);
      s16x8 b0 = *(const s16x8*)(buf + oB[kk][0]);
      s16x8 b1 = *(const s16x8*)(buf + oB[kk][1]);
      __builtin_amdgcn_s_setprio(1);
      acc[0][0] = __builtin_amdgcn_mfma_f32_32x32x16_bf16(a0, b0, acc[0][0], 0, 0, 0);
      acc[0][1] = __builtin_amdgcn_mfma_f32_32x32x16_bf16(a0, b1, acc[0][1], 0, 0, 0);
      acc[1][0] = __builtin_amdgcn_mfma_f32_32x32x16_bf16(a1, b0, acc[1][0], 0, 0, 0);
      acc[1][1] = __builtin_amdgcn_mfma_f32_32x32x16_bf16(a1, b1, acc[1][1], 0, 0, 0);
      __builtin_amdgcn_s_setprio(0);
    }
    BARF;                      // all reads of buf done -> safe to overwrite
    if (t + 2 < NT) stage(t + 2);
  }
}

// C coordinate helpers (32x32 frag): caller supplies wm/wn/hi/l
#define CROW(mi, reg) ((wv >> 1) * 64 + (mi) * 32 + ((reg) & 3) + 8 * ((reg) >> 2) + 4 * hi)
#define CCOL(ni)      ((wv & 1) * 64 + (ni) * 32 + (l & 31))

// ---------------------------------------------------------------------------
// K0: fused fp32->bf16 cast; Qb transposed to [b][t][d]; weights copied.
// dst arena contiguous: Qb | Wqb | Wkb | Wvb | Wob
// ---------------------------------------------------------------------------
__global__ __launch_bounds__(256) void k_cvt_all(
    const float* __restrict__ Q,  const float* __restrict__ Wq,
    const float* __restrict__ Wk, const float* __restrict__ Wv,
    const float* __restrict__ Wo, short* __restrict__ dst)
{
  constexpr int N_Q = 524288;              // 1024*8*256/4
  constexpr int N_W = 262144;              // 8*512*256/4
  constexpr int TOT = N_Q + 4 * N_W;
  int i  = blockIdx.x * 256 + threadIdx.x;
  int st = gridDim.x * 256;
  for (; i < TOT; i += st) {
    const float* s; int off;
    if (i < N_Q) {
      // dst [b][t][d]: b = i>>16, t = (i>>6)&1023, d4 = i&63 ; src [t][b][d]
      int b = i >> 16, t = (i >> 6) & 1023, d4 = i & 63;
      s = Q; off = (t * 8 + b) * 64 + d4;
    }
    else if (i < N_Q + N_W)     { s = Wq; off = i - N_Q; }
    else if (i < N_Q + 2 * N_W) { s = Wk; off = i - N_Q - N_W; }
    else if (i < N_Q + 3 * N_W) { s = Wv; off = i - N_Q - 2 * N_W; }
    else                        { s = Wo; off = i - N_Q - 3 * N_W; }
    float4 v = ((const float4*)s)[off];
    s16x4 o = { f2bf(v.x), f2bf(v.y), f2bf(v.z), f2bf(v.w) };
    ((s16x4*)dst)[i] = o;
  }
}

// ---------------------------------------------------------------------------
// K1: QKV projection. m = b*T+t; C[m,e] = sum_d Qb[m,d]*W[h,e,d] + bias
// grid (32, 4, 3*HG); out q/k/v layout [hh][m][e] (= [hh][b][t][e])
// ---------------------------------------------------------------------------
__global__ __launch_bounds__(512, 4) void k_proj(
    const short* __restrict__ Qb,
    const short* __restrict__ Wqb, const short* __restrict__ Wkb, const short* __restrict__ Wvb,
    const float* __restrict__ bq, const float* __restrict__ bk, const float* __restrict__ bv,
    short* __restrict__ qb, short* __restrict__ kb, short* __restrict__ vb,
    int h0, int HG)
{
  __shared__ short lds[24576];
  // T1 bijective XCD swizzle (nwg = 384*HG, divisible by 8)
  int orig = blockIdx.x + (blockIdx.y << 5) + blockIdx.z * 128;
  int q8   = (384 * HG) >> 3;
  int swz  = (orig & 7) * q8 + (orig >> 3);
  const int bx = swz & 31, by = (swz >> 5) & 3, bz = swz >> 7;
  const int p = bz / HG, hh = bz % HG, h = h0 + hh;

  const short* W    = (p == 0 ? Wqb : p == 1 ? Wkb : Wvb) + ((size_t)h * EH + (size_t)by * 128) * DIN;
  const float* bias = (p == 0 ? bq  : p == 1 ? bk  : bv ) + h * EH + by * 128;
  short* outp       = (p == 0 ? qb  : p == 1 ? kb  : vb ) + (size_t)hh * BATCH * T_SEQ * EH;
  const short* Ag   = Qb + (size_t)bx * 256 * DIN;

  f32x16 acc[2][2] = {};
  gemm32<DIN / 32>(Ag, DIN, W, DIN, lds, acc);

  const int l = threadIdx.x & 63, wv = threadIdx.x >> 6, hi = l >> 5;
#pragma unroll
  for (int ni = 0; ni < 2; ++ni) {
    int coll = CCOL(ni);
    float bia = bias[coll];
    int e = by * 128 + coll;
#pragma unroll
    for (int mi = 0; mi < 2; ++mi)
#pragma unroll
      for (int reg = 0; reg < 16; ++reg) {
        int m = bx * 256 + CROW(mi, reg);
        outp[(size_t)m * EH + e] = f2bf(acc[mi][ni][reg] + bia);
      }
  }
}

// ---------------------------------------------------------------------------
// K3a: P[t,s] = exp(SCALE*q.k) bf16 + per-block column sums
// grid (4, 8, HG*8): bx = 256-row t-tile, by = 128-col s-tile
// colpart[(z*4+bx)*T + s] = sum over this block's 256 t of exp
// ---------------------------------------------------------------------------
__global__ __launch_bounds__(512, 4) void k_pgen(
    const short* __restrict__ qb, const short* __restrict__ kb,
    short* __restrict__ Pbuf, float* __restrict__ colpart, int HG)
{
  __shared__ short lds[24576];
  int orig = blockIdx.x + (blockIdx.y << 2) + (blockIdx.z << 5);
  int q8   = (256 * HG) >> 3;
  int swz  = (orig & 7) * q8 + (orig >> 3);
  const int bx = swz & 3, by = (swz >> 2) & 7, z = swz >> 5;

  const short* Ag = qb + (size_t)z * T_SEQ * EH + (size_t)bx * 256 * EH;
  const short* Bg = kb + (size_t)z * T_SEQ * EH + (size_t)by * 128 * EH;

  f32x16 acc[2][2] = {};
  gemm32<EH / 32>(Ag, EH, Bg, EH, lds, acc);

  short* Pb = Pbuf + (size_t)z * T_SEQ * T_SEQ;
  const int l = threadIdx.x & 63, wv = threadIdx.x >> 6, hi = l >> 5;

  float cs[2] = {0.f, 0.f};
#pragma unroll
  for (int ni = 0; ni < 2; ++ni) {
    int s = by * 128 + CCOL(ni);
#pragma unroll
    for (int mi = 0; mi < 2; ++mi)
#pragma unroll
      for (int reg = 0; reg < 16; ++reg) {
        int tq = bx * 256 + CROW(mi, reg);
        float ev = __expf(acc[mi][ni][reg] * SCALE);
        cs[ni] += ev;
        Pb[(size_t)tq * T_SEQ + s] = f2bf(ev);
      }
  }
  // cs covers this wave's 32 rows for its hi; fold other half-wave:
  cs[0] += __shfl_xor(cs[0], 32);
  cs[1] += __shfl_xor(cs[1], 32);
  float* csL = (float*)lds;     // [4 wm][128 cols], reuse LDS post-barrier
  if (l < 32) {
#pragma unroll
    for (int ni = 0; ni < 2; ++ni) csL[(wv >> 1) * 128 + CCOL(ni)] = cs[ni];
  }
  __syncthreads();
  if (threadIdx.x < 128) {
    float tot = csL[threadIdx.x] + csL[128 + threadIdx.x] +
                csL[256 + threadIdx.x] + csL[384 + threadIdx.x];
    colpart[((size_t)z * 4 + bx) * T_SEQ + by * 128 + threadIdx.x] = tot;
  }
}

// ---------------------------------------------------------------------------
// K_tr (+invsum): vbT[z][e][s] = vb[z][s][e] / colsum[z][s]
// ---------------------------------------------------------------------------
__global__ __launch_bounds__(256) void k_tr(const short* __restrict__ vb,
                                            const float* __restrict__ colpart,
                                            short* __restrict__ vbT)
{
  __shared__ float tl[64][65];
  __shared__ float invL[64];
  const int bx = blockIdx.x, by = blockIdx.y, z = blockIdx.z;
  const short* in  = vb  + (size_t)z * T_SEQ * EH;
  short*       out = vbT + (size_t)z * EH * T_SEQ;
  const int tid = threadIdx.x;

  if (tid < 64) {
    int s = bx * 64 + tid;
    float sum = 0.f;
#pragma unroll
    for (int tt = 0; tt < 4; ++tt) sum += colpart[((size_t)z * 4 + tt) * T_SEQ + s];
    invL[tid] = 1.0f / sum;
  }
  __syncthreads();

#pragma unroll
  for (int rep = 0; rep < 2; ++rep) {
    int s_l = (tid >> 3) + rep * 32;
    int e_l = (tid & 7) * 8;
    s16x8 v = *(const s16x8*)&in[(size_t)(bx * 64 + s_l) * EH + by * 64 + e_l];
    float iv = invL[s_l];
#pragma unroll
    for (int j = 0; j < 8; ++j) tl[s_l][e_l + j] = bf2f(v[j]) * iv;
  }
  __syncthreads();
#pragma unroll
  for (int rep = 0; rep < 2; ++rep) {
    int e_w = (tid >> 3) + rep * 32;
    int s_w = (tid & 7) * 8;
    s16x8 o;
#pragma unroll
    for (int j = 0; j < 8; ++j) o[j] = f2bf(tl[s_w + j][e_w]);
    *(s16x8*)&out[(size_t)(by * 64 + e_w) * T_SEQ + bx * 64 + s_w] = o;
  }
}

// ---------------------------------------------------------------------------
// K3b: O[t,e] = sum_s P[t,s]*vbT[e,s] -> Hmat[(b*T+t), h*EH+e] bf16
// grid (4, 4, HG*8)
// ---------------------------------------------------------------------------
__global__ __launch_bounds__(512, 4) void k_ogemm(
    const short* __restrict__ Pbuf, const short* __restrict__ vbT,
    short* __restrict__ Hmat, int h0, int HG)
{
  __shared__ short lds[24576];
  int orig = blockIdx.x + (blockIdx.y << 2) + (blockIdx.z << 4);
  int q8   = (128 * HG) >> 3;
  int swz  = (orig & 7) * q8 + (orig >> 3);
  const int bx = swz & 3, by = (swz >> 2) & 3, z = swz >> 4;

  const short* Ag = Pbuf + (size_t)z * T_SEQ * T_SEQ + (size_t)bx * 256 * T_SEQ;
  const short* Bg = vbT  + (size_t)z * EH * T_SEQ    + (size_t)by * 128 * T_SEQ;

  f32x16 acc[2][2] = {};
  gemm32<T_SEQ / 32>(Ag, T_SEQ, Bg, T_SEQ, lds, acc);

  const int hh = z >> 3, b = z & 7, h = h0 + hh;
  const int l = threadIdx.x & 63, wv = threadIdx.x >> 6, hi = l >> 5;
#pragma unroll
  for (int ni = 0; ni < 2; ++ni) {
    int e = by * 128 + CCOL(ni);
#pragma unroll
    for (int mi = 0; mi < 2; ++mi)
#pragma unroll
      for (int reg = 0; reg < 16; ++reg) {
        int tq = bx * 256 + CROW(mi, reg);
        Hmat[((size_t)b * T_SEQ + tq) * HE + (size_t)h * EH + e] = f2bf(acc[mi][ni][reg]);
      }
  }
}

// ---------------------------------------------------------------------------
// K4a: split-K(4) output GEMM. part[ks][m][d] over K=1024 slice
// grid (32, 2, 4)
// ---------------------------------------------------------------------------
__global__ __launch_bounds__(512, 4) void k_final(
    const short* __restrict__ Hmat, const short* __restrict__ Wob,
    float* __restrict__ part)
{
  __shared__ short lds[24576];
  int orig = blockIdx.x + (blockIdx.y << 5) + (blockIdx.z << 6);
  int swz  = (orig & 7) * 32 + (orig >> 3);     // nwg = 256
  const int bx = swz & 31, by = (swz >> 5) & 1, ks = swz >> 6;

  const short* Ag = Hmat + (size_t)bx * 256 * HE + (size_t)ks * 1024;
  const short* Bg = Wob  + (size_t)by * 128 * HE + (size_t)ks * 1024;

  f32x16 acc[2][2] = {};
  gemm32<1024 / 32>(Ag, HE, Bg, HE, lds, acc);

  float* pp = part + (size_t)ks * (T_SEQ * BATCH) * DIN;
  const int l = threadIdx.x & 63, wv = threadIdx.x >> 6, hi = l >> 5;
#pragma unroll
  for (int ni = 0; ni < 2; ++ni) {
    int d = by * 128 + CCOL(ni);
#pragma unroll
    for (int mi = 0; mi < 2; ++mi)
#pragma unroll
      for (int reg = 0; reg < 16; ++reg) {
        int m = bx * 256 + CROW(mi, reg);
        pp[(size_t)m * DIN + d] = acc[mi][ni][reg];
      }
  }
}

// K4b: out[(t*B+b), d] = sum_ks part[ks][(b*T+t)][d] + bo[d]
__global__ __launch_bounds__(256) void k_red(const float* __restrict__ part,
                                             const float* __restrict__ bo,
                                             float* __restrict__ out)
{
  int i = blockIdx.x * 256 + threadIdx.x;   // over 8192*64 float4s
  int m = i >> 6, d4 = i & 63;
  float4 s = ((const float4*)part)[i];
#pragma unroll
  for (int ks = 1; ks < 4; ++ks) {
    float4 p = ((const float4*)(part + (size_t)ks * T_SEQ * BATCH * DIN))[i];
    s.x += p.x; s.y += p.y; s.z += p.z; s.w += p.w;
  }
  float4 b4 = ((const float4*)bo)[d4];
  s.x += b4.x; s.y += b4.y; s.z += b4.z; s.w += b4.w;
  int t = m & 1023, b = m >> 10;
  ((float4*)out)[(t * 8 + b) * 64 + d4] = s;
}

// ---------------------------------------------------------------------------
extern "C" void kernel_launch(void* const* d_in, const int* in_sizes, int n_in,
                              void* d_out, int out_size, void* d_ws, size_t ws_size,
                              hipStream_t stream)
{
  const float* Q  = (const float*)d_in[0];
  const float* Wq = (const float*)d_in[1];
  const float* bq = (const float*)d_in[2];
  const float* Wk = (const float*)d_in[3];
  const float* bk = (const float*)d_in[4];
  const float* Wv = (const float*)d_in[5];
  const float* bv = (const float*)d_in[6];
  const float* Wo = (const float*)d_in[7];
  const float* bo = (const float*)d_in[8];
  float* out = (float*)d_out;

  // ---- sizes ----
  const size_t QB_B   = (size_t)T_SEQ * BATCH * DIN * 2;       //  4 MiB
  const size_t W_B    = (size_t)NH * EH * DIN * 2;             //  2 MiB each
  const size_t WO_B   = (size_t)DIN * HE * 2;                  //  2 MiB
  const size_t HMAT_B = (size_t)T_SEQ * BATCH * HE * 2;        // 64 MiB
  const size_t PART_B = (size_t)4 * T_SEQ * BATCH * DIN * 4;   // 32 MiB
  const size_t QKV1   = (size_t)BATCH * T_SEQ * EH * 2;        //  8 MiB / head
  const size_t P1     = (size_t)BATCH * T_SEQ * T_SEQ * 2;     // 16 MiB / head
  const size_t CP1    = (size_t)BATCH * 4 * T_SEQ * 4;         // 128 KiB / head
  const size_t inputsB = QB_B + 3 * W_B + WO_B;                // 12 MiB contiguous

  // ---- largest HG whose aliased plan fits (vbT<->qb, part<->P) ----
  int HG = 8;
  for (; HG > 1; HG >>= 1) {
    size_t share = ((size_t)HG * P1 > PART_B) ? (size_t)HG * P1 : PART_B;
    size_t tot = inputsB + 3 * (size_t)HG * QKV1 + share + HMAT_B
               + (size_t)HG * CP1 + 8192;
    if (tot <= ws_size) break;
  }
  size_t shareB = ((size_t)HG * P1 > PART_B) ? (size_t)HG * P1 : PART_B;

  char* w = (char*)d_ws;
  auto alloc = [&](size_t bytes) {
    char* p = w;
    w += (bytes + 255) & ~(size_t)255;
    return p;
  };
  short* Qb   = (short*)alloc(QB_B);
  short* Wqb  = (short*)alloc(W_B);
  short* Wkb  = (short*)alloc(W_B);
  short* Wvb  = (short*)alloc(W_B);
  short* Wob  = (short*)alloc(WO_B);
  float* cpart= (float*)alloc((size_t)HG * CP1);
  short* qb   = (short*)alloc((size_t)HG * QKV1);   // aliased by vbT after pgen
  short* kb   = (short*)alloc((size_t)HG * QKV1);
  short* vb   = (short*)alloc((size_t)HG * QKV1);
  char*  shr  = alloc(shareB);                      // P during loop; part after
  short* Hmat = (short*)alloc(HMAT_B);

  short* vbT  = qb;
  short* Pbuf = (short*)shr;
  float* part = (float*)shr;

  k_cvt_all<<<dim3(2048), 256, 0, stream>>>(Q, Wq, Wk, Wv, Wo, Qb);

  for (int h0 = 0; h0 < NH; h0 += HG) {
    k_proj <<<dim3(32, 4, 3 * HG),  512, 0, stream>>>(Qb, Wqb, Wkb, Wvb, bq, bk, bv,
                                                      qb, kb, vb, h0, HG);
    k_pgen <<<dim3(4, 8, HG * 8), 512, 0, stream>>>(qb, kb, Pbuf, cpart, HG);
    k_tr   <<<dim3(16, 8, HG * 8), 256, 0, stream>>>(vb, cpart, vbT);
    k_ogemm<<<dim3(4, 4, HG * 8), 512, 0, stream>>>(Pbuf, vbT, Hmat, h0, HG);
  }
  k_final<<<dim3(32, 2, 4), 512, 0, stream>>>(Hmat, Wob, part);
  k_red  <<<dim3(T_SEQ * BATCH * DIN / 4 / 256), 256, 0, stream>>>(part, bo, out);
}